// Round 16
// baseline (255.707 us; speedup 1.0000x reference)
//
#include <hip/hip_runtime.h>
#include <hip/hip_bf16.h>
#include <cstdint>

typedef unsigned short u16;
typedef __attribute__((ext_vector_type(8))) short short8;
typedef __attribute__((ext_vector_type(4))) short short4v;
typedef __attribute__((ext_vector_type(4))) float f32x4;

#define HW_N 16384   // H*W
#define CCH  256     // C
#define BATCH 8
#define NHEAD 8
#define HEADC 32

static __device__ __forceinline__ float bf2f(u16 u){
    union { float f; uint32_t i; } x; x.i = ((uint32_t)u) << 16; return x.f;
}
static __device__ __forceinline__ u16 f2bf(float f){
    union { float f; uint32_t i; } x; x.f = f;
    uint32_t r = x.i + 0x7fffu + ((x.i >> 16) & 1u);   // round-to-nearest-even
    return (u16)(r >> 16);
}

#define GLD16(gp, lp) __builtin_amdgcn_global_load_lds( \
    (const __attribute__((address_space(1))) uint32_t*)(gp), \
    (__attribute__((address_space(3))) uint32_t*)(lp), 16, 0, 0)

// ---------------------------------------------------------------------------
// K0a: x [B,C,N] fp32 -> xb [B*N, C] bf16  (transpose + cast, LDS-tiled)
// ---------------------------------------------------------------------------
__global__ __launch_bounds__(256) void k_transpose_cast(const float* __restrict__ x,
                                                        u16* __restrict__ xb){
    __shared__ float tile[64][65];
    int b = blockIdx.z, ct = blockIdx.y, nt = blockIdx.x;
    int t = threadIdx.x;
    const float* src = x + ((size_t)b * CCH + ct * 64) * HW_N + nt * 64;
    #pragma unroll
    for (int it = 0; it < 16; ++it){
        int f = it * 256 + t;
        int i = f >> 6, j = f & 63;              // i = c-local, j = n-local
        tile[i][j] = src[(size_t)i * HW_N + j];  // coalesced (j fastest)
    }
    __syncthreads();
    u16* dst = xb + ((size_t)b * HW_N + nt * 64) * CCH + ct * 64;
    #pragma unroll
    for (int it = 0; it < 16; ++it){
        int f = it * 256 + t;
        int jj = f >> 6, ii = f & 63;            // jj = n-local, ii = c-local
        dst[(size_t)jj * CCH + ii] = f2bf(tile[ii][jj]);  // coalesced writes
    }
}

// ---------------------------------------------------------------------------
// K0b: weight prep. wkv_b[h*64 + s*32 + d] <- w_qkv row (h*96 + 32 + s*32 + d)
// ---------------------------------------------------------------------------
__global__ __launch_bounds__(256) void k_weight_prep(const float* __restrict__ w_qkv,
                                                     const float* __restrict__ b_qkv,
                                                     const float* __restrict__ w_o1,
                                                     const float* __restrict__ w_o2,
                                                     u16* __restrict__ wkv_b,
                                                     float* __restrict__ bkv_re,
                                                     u16* __restrict__ w_o1_b,
                                                     u16* __restrict__ w_o2_b){
    int id = blockIdx.x * 256 + threadIdx.x;
    if (id < 512 * 256){
        int r = id >> 8, c = id & 255;
        int h = r >> 6, s = (r >> 5) & 1, d = r & 31;
        int srow = h * 96 + 32 + s * 32 + d;
        wkv_b[id] = f2bf(w_qkv[(size_t)srow * 256 + c]);
        if (c == 0) bkv_re[r] = b_qkv[srow];
    } else {
        int id2 = id - 512 * 256;
        if (id2 < 65536)       w_o1_b[id2]         = f2bf(w_o1[id2]);
        else if (id2 < 131072) w_o2_b[id2 - 65536] = f2bf(w_o2[id2 - 65536]);
    }
}

// ---------------------------------------------------------------------------
// K1 fused (round-8 version): kv-projection GEMM + per-head LN + kv partial
// reduce. Single-buffer 32KB staging, __syncthreads schedule.
// ---------------------------------------------------------------------------
__global__ __launch_bounds__(256, 2) void k_gemm_kv(const u16* __restrict__ A,
                                                    const u16* __restrict__ Bt,
                                                    const float* __restrict__ bkv,
                                                    const float* __restrict__ kln_w,
                                                    const float* __restrict__ kln_b,
                                                    const float* __restrict__ vln_w,
                                                    const float* __restrict__ vln_b,
                                                    float* __restrict__ kvpart){
    __shared__ __align__(16) u16 sh[16384];     // staging, then LN'd k/v tiles
    u16* lsA = sh;
    u16* lsB = sh + 8192;

    int lin = blockIdx.x + 4 * (blockIdx.y + 128 * blockIdx.z);
    int bx = (lin >> 3) & 3;
    int rest = (lin & 7) | ((lin >> 5) << 3);
    int by = rest & 127;
    int bz = rest >> 7;

    int row0 = bz * HW_N + by * 128;
    int col0 = bx * 128;

    int t = threadIdx.x;
    int wid = t >> 6, lane = t & 63;
    int wr = wid >> 1, wc = wid & 1;
    int q = lane >> 4, q4 = q * 4, lrow = lane & 15;

    f32x4 acc[4][4];
    #pragma unroll
    for (int i = 0; i < 4; ++i)
        #pragma unroll
        for (int j = 0; j < 4; ++j) acc[i][j] = (f32x4)0.0f;

    for (int kt = 0; kt < 4; ++kt){
        int c0 = kt * 64;
        #pragma unroll
        for (int it = 0; it < 4; ++it){
            int f  = it * 256 + t;
            int fs = f ^ ((f >> 3) & 7);
            int r  = f >> 3, c8 = (fs & 7) * 8;
            GLD16(&A [((size_t)(row0 + r)) * 256 + c0 + c8], &lsA[f * 8]);
            GLD16(&Bt[((size_t)(col0 + r)) * 256 + c0 + c8], &lsB[f * 8]);
        }
        __syncthreads();
        #pragma unroll
        for (int ks = 0; ks < 2; ++ks){
            int lk = q * 8 + ks * 32;
            short8 af[4], bfr[4];
            #pragma unroll
            for (int mi = 0; mi < 4; ++mi){
                int row = wr * 64 + mi * 16 + lrow;
                int e = (row * 64 + lk) ^ ((row & 7) << 3);
                af[mi] = *(const short8*)&lsA[e];
            }
            #pragma unroll
            for (int ni = 0; ni < 4; ++ni){
                int row = wc * 64 + ni * 16 + lrow;
                int e = (row * 64 + lk) ^ ((row & 7) << 3);
                bfr[ni] = *(const short8*)&lsB[e];
            }
            #pragma unroll
            for (int mi = 0; mi < 4; ++mi)
                #pragma unroll
                for (int ni = 0; ni < 4; ++ni)
                    acc[mi][ni] = __builtin_amdgcn_mfma_f32_16x16x32_bf16(
                        bfr[ni], af[mi], acc[mi][ni], 0, 0, 0);   // swapped
        }
        __syncthreads();
    }

    int h = 2 * bx + wc;
    float bv[4][4], lwv[4][4], lbv[4][4];
    #pragma unroll
    for (int ni = 0; ni < 4; ++ni){
        const float* w  = (ni < 2) ? kln_w : vln_w;
        const float* bb = (ni < 2) ? kln_b : vln_b;
        #pragma unroll
        for (int r = 0; r < 4; ++r){
            int de = (ni & 1) * 16 + q4 + r;
            bv[ni][r]  = bkv[col0 + wc * 64 + ni * 16 + q4 + r];
            lwv[ni][r] = w[h * 32 + de];
            lbv[ni][r] = bb[h * 32 + de];
        }
    }

    #pragma unroll
    for (int mi = 0; mi < 4; ++mi){
        float ks = 0.f, ksq = 0.f, vs = 0.f, vsq = 0.f;
        #pragma unroll
        for (int ni = 0; ni < 4; ++ni)
            #pragma unroll
            for (int r = 0; r < 4; ++r){
                float t2 = acc[mi][ni][r] + bv[ni][r];
                acc[mi][ni][r] = t2;
                if (ni < 2){ ks += t2; ksq += t2 * t2; }
                else       { vs += t2; vsq += t2 * t2; }
            }
        ks  += __shfl_xor(ks, 16);  ks  += __shfl_xor(ks, 32);
        ksq += __shfl_xor(ksq, 16); ksq += __shfl_xor(ksq, 32);
        vs  += __shfl_xor(vs, 16);  vs  += __shfl_xor(vs, 32);
        vsq += __shfl_xor(vsq, 16); vsq += __shfl_xor(vsq, 32);
        float muk = ks * 0.03125f, muv = vs * 0.03125f;
        float rsk = rsqrtf(fmaxf(ksq * 0.03125f - muk * muk, 0.f) + 1e-5f);
        float rsv = rsqrtf(fmaxf(vsq * 0.03125f - muv * muv, 0.f) + 1e-5f);
        int n = wr * 64 + mi * 16 + lrow;
        #pragma unroll
        for (int ni = 0; ni < 4; ++ni){
            float mu = (ni < 2) ? muk : muv;
            float rs = (ni < 2) ? rsk : rsv;
            #pragma unroll
            for (int r = 0; r < 4; ++r){
                int d = (ni & 1) * 16 + q4 + r;
                float val = (acc[mi][ni][r] - mu) * rs * lwv[ni][r] + lbv[ni][r];
                int byteoff = ((wc * 2 + (ni >> 1)) << 13) + (d << 8) + (n << 1);
                byteoff ^= (d & 7) << 4;
                *(u16*)((char*)sh + byteoff) = f2bf(val);
            }
        }
    }
    __syncthreads();

    if (wid < 2){
        f32x4 a2[2][2];
        #pragma unroll
        for (int i = 0; i < 2; ++i)
            #pragma unroll
            for (int j = 0; j < 2; ++j) a2[i][j] = (f32x4)0.0f;
        #pragma unroll
        for (int ks2 = 0; ks2 < 4; ++ks2){
            int n0 = q * 8 + ks2 * 32;
            short8 kf[2], vf[2];
            #pragma unroll
            for (int mi = 0; mi < 2; ++mi){
                int d = mi * 16 + lrow;
                int bko = ((wid * 2 + 0) << 13) + (d << 8) + (n0 << 1);
                int bvo = ((wid * 2 + 1) << 13) + (d << 8) + (n0 << 1);
                bko ^= (d & 7) << 4;
                bvo ^= (d & 7) << 4;
                kf[mi] = *(const short8*)((char*)sh + bko);
                vf[mi] = *(const short8*)((char*)sh + bvo);
            }
            #pragma unroll
            for (int mi = 0; mi < 2; ++mi)
                #pragma unroll
                for (int ni = 0; ni < 2; ++ni)
                    a2[mi][ni] = __builtin_amdgcn_mfma_f32_16x16x32_bf16(
                        kf[mi], vf[ni], a2[mi][ni], 0, 0, 0);
        }
        float* dst = kvpart + (((size_t)(bz * 128 + by)) * 8 + 2 * bx + wid) * 1024;
        #pragma unroll
        for (int mi = 0; mi < 2; ++mi)
            #pragma unroll
            for (int ni = 0; ni < 2; ++ni)
                #pragma unroll
                for (int r = 0; r < 4; ++r)
                    dst[(mi * 16 + q4 + r) * 32 + ni * 16 + lrow] = a2[mi][ni][r];
    }
}

// ---------------------------------------------------------------------------
// K2: reduce kv partials (128 chunks), form wq_eff[b,h,e,c] and beff[b,h,e]
// ---------------------------------------------------------------------------
__global__ __launch_bounds__(256) void k_wqeff(const float* __restrict__ kvpart,
                                               const float* __restrict__ w_qkv,
                                               const float* __restrict__ b_qkv,
                                               u16* __restrict__ wq_eff_b,
                                               float* __restrict__ beff){
    __shared__ float kv[1024];   // [d*32 + e]
    int h = blockIdx.x, b = blockIdx.y;
    int t = threadIdx.x;
    f32x4 s = (f32x4)0.0f;
    for (int p = 0; p < 128; ++p){
        f32x4 v = *(const f32x4*)(kvpart + (((size_t)b * 128 + p) * 8 + h) * 1024 + t * 4);
        s = s + v;
    }
    const float invN = 1.0f / (float)HW_N;
    #pragma unroll
    for (int i = 0; i < 4; ++i) kv[t * 4 + i] = s[i] * invN;
    __syncthreads();

    float wcol[32];
    #pragma unroll
    for (int d = 0; d < 32; ++d)
        wcol[d] = w_qkv[((size_t)(h * 96 + d)) * 256 + t];
    for (int e = 0; e < 32; ++e){
        float s2 = 0.f;
        #pragma unroll
        for (int d = 0; d < 32; ++d) s2 += wcol[d] * kv[d * 32 + e];
        wq_eff_b[(((size_t)b * 256) + h * 32 + e) * 256 + t] = f2bf(s2);
    }
    if (t < 32){
        float s3 = 0.f;
        #pragma unroll
        for (int d = 0; d < 32; ++d) s3 += b_qkv[h * 96 + d] * kv[d * 32 + t];
        beff[b * 256 + h * 32 + t] = s3;
    }
}

// ---------------------------------------------------------------------------
// K3 fused v11 = v10 (triple-buffer, one barrier/phase) + bf16 residual from
// the L1-HOT xb panel: stage-3's residual is loaded at kernel start as packed
// bf16 (8 VGPRs) from the SAME xb rows the I-preload fetches — the fp32 x
// stream (134 MB through L3, serial in the stage-3 epilogue) disappears.
// Accuracy: out = y2 + bf16(x); extra error <= 2^-9*|x| ~ 0.011.
// ---------------------------------------------------------------------------
#define STAGE_B(BT, KT, BUF) do {                                             \
    _Pragma("unroll")                                                         \
    for (int it_ = 0; it_ < 2; ++it_){                                        \
        int f_ = it_ * 512 + t;                                               \
        int o_ = f_ >> 2, sl_ = f_ & 3;                                       \
        GLD16(&(BT)[(size_t)o_ * 256 + (KT) * 32 + (sl_ ^ ((o_ >> 1) & 3)) * 8],\
              &(BUF)[f_ * 8]);                                                \
    }                                                                         \
} while(0)

#define ZACC do {                                                             \
    _Pragma("unroll") for (int i_ = 0; i_ < 4; ++i_)                          \
    _Pragma("unroll") for (int j_ = 0; j_ < 2; ++j_)                          \
        acc[i_][j_] = (f32x4)0.0f;                                            \
} while(0)

// Precondition: Bs[0] <- tile0, Bs[1] <- tile1 staged (may be in flight).
// One barrier per phase; stage tile kt+2 into Bs[(kt+2)%3] post-barrier.
#define GEMM_STAGE_TRI(BT, SWAPPED) do {                                      \
    _Pragma("unroll")                                                         \
    for (int kt = 0; kt < 8; ++kt){                                           \
        if (kt < 7) asm volatile("s_waitcnt vmcnt(2)" ::: "memory");          \
        else        asm volatile("s_waitcnt vmcnt(0)" ::: "memory");          \
        __builtin_amdgcn_s_barrier();                                         \
        if (kt < 6) STAGE_B(BT, kt + 2, Bs[(kt + 2) % 3]);                    \
        __builtin_amdgcn_sched_barrier(0);                                    \
        const u16* Bc = Bs[kt % 3];                                           \
        short8 af[4], bf[2];                                                  \
        _Pragma("unroll")                                                     \
        for (int ni = 0; ni < 2; ++ni){                                       \
            int o_ = wid * 32 + ni * 16 + lrow;                               \
            bf[ni] = *(const short8*)((const char*)Bc + o_ * 64               \
                                      + ((q ^ ((o_ >> 1) & 3)) << 4));        \
        }                                                                     \
        _Pragma("unroll")                                                     \
        for (int mi = 0; mi < 4; ++mi){                                       \
            int n_ = mi * 16 + lrow;                                          \
            int sl_ = (kt * 4 + q) ^ (n_ & 7);                                \
            af[mi] = *(const short8*)((const char*)I + n_ * 512 + (sl_ << 4));\
        }                                                                     \
        __builtin_amdgcn_s_setprio(1);                                        \
        _Pragma("unroll")                                                     \
        for (int mi = 0; mi < 4; ++mi)                                        \
            _Pragma("unroll")                                                 \
            for (int ni = 0; ni < 2; ++ni)                                    \
                acc[mi][ni] = (SWAPPED)                                       \
                    ? __builtin_amdgcn_mfma_f32_16x16x32_bf16(                \
                          bf[ni], af[mi], acc[mi][ni], 0, 0, 0)               \
                    : __builtin_amdgcn_mfma_f32_16x16x32_bf16(                \
                          af[mi], bf[ni], acc[mi][ni], 0, 0, 0);              \
        __builtin_amdgcn_s_setprio(0);                                        \
    }                                                                         \
} while(0)

#define LDS_FENCE_BARRIER() do {                                              \
    asm volatile("s_waitcnt lgkmcnt(0)" ::: "memory");                        \
    __builtin_amdgcn_s_barrier();                                             \
    __builtin_amdgcn_sched_barrier(0);                                        \
} while(0)

__global__ __launch_bounds__(512, 4) void k_fused3(const u16* __restrict__ xb,
                                                   const u16* __restrict__ wq_effb,
                                                   const float* __restrict__ beff,
                                                   const u16* __restrict__ w_o1_b,
                                                   const float* __restrict__ b_o1,
                                                   const u16* __restrict__ w_o2_b,
                                                   const float* __restrict__ b_o2,
                                                   const float* __restrict__ x,
                                                   float* __restrict__ out){
    __shared__ __align__(16) u16 I[16384];        // 32 KB persistent panel
    __shared__ __align__(16) u16 Bs[3][8192];     // 3 x 16 KB B rotation

    int d = blockIdx.x;                 // 2048 blocks
    int bz = d & 7, nb = d >> 3;        // batch-per-XCD remap
    size_t row0 = (size_t)bz * HW_N + (size_t)nb * 64;

    int t = threadIdx.x, wid = t >> 6, lane = t & 63;   // wid 0..7
    int lrow = lane & 15, q = lane >> 4, q4 = q * 4;

    const u16* B1 = wq_effb + (size_t)bz * 65536;

    // ---- preload xb panel into I ----
    #pragma unroll
    for (int it = 0; it < 4; ++it){
        int f = it * 512 + t;
        int n = f >> 5, slot = f & 31;
        GLD16(&xb[(row0 + n) * 256 + (size_t)((slot ^ (n & 7)) * 8)], &I[f * 8]);
    }
    // ---- bf16 residual regs from the SAME xb rows (L1/L2-hot, 8 VGPRs) ----
    short4v xq[2][4];
    #pragma unroll
    for (int ni = 0; ni < 2; ++ni)
        #pragma unroll
        for (int mi = 0; mi < 4; ++mi){
            int o = wid * 32 + ni * 16 + lrow;
            #pragma unroll
            for (int r = 0; r < 4; ++r)
                xq[ni][mi][r] = (short)xb[(row0 + mi * 16 + q4 + r) * 256 + o];
        }
    STAGE_B(B1, 0, Bs[0]);
    STAGE_B(B1, 1, Bs[1]);
    // phase-0 vmcnt(2) drains I, xq, tile0; tile1 stays in flight.

    f32x4 acc[4][2];

    // ================= stage 1: ret = I @ wqeff^T + beff + I ================
    ZACC;
    GEMM_STAGE_TRI(B1, true);
    __syncthreads();                    // all waves done READING I
    #pragma unroll
    for (int ni = 0; ni < 2; ++ni){
        int o0 = wid * 32 + ni * 16 + q4;
        f32x4 be = *(const f32x4*)&beff[bz * 256 + o0];
        #pragma unroll
        for (int mi = 0; mi < 4; ++mi){
            int n = mi * 16 + lrow;
            int byte = (n * 512 + o0 * 2) ^ ((n & 7) << 4);
            short4v rv = *(const short4v*)((const char*)I + byte);
            short4v pk;
            #pragma unroll
            for (int r = 0; r < 4; ++r)
                pk[r] = (short)f2bf(acc[mi][ni][r] + be[r] + bf2f((u16)rv[r]));
            *(short4v*)((char*)I + byte) = pk;
        }
    }
    LDS_FENCE_BARRIER();                // I rewrite visible; Bs reads all past
    STAGE_B(w_o1_b, 0, Bs[0]);          // stage-2 tiles 0,1
    STAGE_B(w_o1_b, 1, Bs[1]);

    // ================= stage 2: y1 = gelu(I @ w_o1^T + b_o1) ================
    ZACC;
    GEMM_STAGE_TRI(w_o1_b, true);
    __syncthreads();
    #pragma unroll
    for (int ni = 0; ni < 2; ++ni){
        int o0 = wid * 32 + ni * 16 + q4;
        f32x4 bo = *(const f32x4*)&b_o1[o0];
        #pragma unroll
        for (int mi = 0; mi < 4; ++mi){
            int n = mi * 16 + lrow;
            int byte = (n * 512 + o0 * 2) ^ ((n & 7) << 4);
            short4v pk;
            #pragma unroll
            for (int r = 0; r < 4; ++r){
                float v = acc[mi][ni][r] + bo[r];
                v = 0.5f * v * (1.0f + erff(v * 0.70710678118654752f));
                pk[r] = (short)f2bf(v);
            }
            *(short4v*)((char*)I + byte) = pk;
        }
    }
    LDS_FENCE_BARRIER();
    STAGE_B(w_o2_b, 0, Bs[0]);          // stage-3 tiles 0,1
    STAGE_B(w_o2_b, 1, Bs[1]);

    // ================= stage 3: out = I @ w_o2^T + b_o2 + bf16(x) ===========
    ZACC;
    GEMM_STAGE_TRI(w_o2_b, false);
    #pragma unroll
    for (int ni = 0; ni < 2; ++ni){
        int o = wid * 32 + ni * 16 + lrow;
        float bo = b_o2[o];
        size_t base = ((size_t)bz * 256 + o) * HW_N + (size_t)nb * 64;
        #pragma unroll
        for (int mi = 0; mi < 4; ++mi){
            int n0 = mi * 16 + q4;
            f32x4 ov;
            #pragma unroll
            for (int r = 0; r < 4; ++r)
                ov[r] = acc[mi][ni][r] + bo + bf2f((u16)xq[ni][mi][r]);
            *(f32x4*)&out[base + n0] = ov;
        }
    }
    (void)x;
}

// ---------------------------------------------------------------------------
extern "C" void kernel_launch(void* const* d_in, const int* in_sizes, int n_in,
                              void* d_out, int out_size, void* d_ws, size_t ws_size,
                              hipStream_t stream){
    const float* x     = (const float*)d_in[0];
    const float* w_qkv = (const float*)d_in[1];
    const float* b_qkv = (const float*)d_in[2];
    const float* kln_w = (const float*)d_in[3];
    const float* kln_b = (const float*)d_in[4];
    const float* vln_w = (const float*)d_in[5];
    const float* vln_b = (const float*)d_in[6];
    const float* w_o1  = (const float*)d_in[7];
    const float* b_o1  = (const float*)d_in[8];
    const float* w_o2  = (const float*)d_in[9];
    const float* b_o2  = (const float*)d_in[10];
    float* out = (float*)d_out;

    const size_t MB = 1u << 20;
    if (ws_size < 266 * MB) return;

    char* ws = (char*)d_ws;
    u16*   xb      = (u16*)(ws);                     // 64 MB
    float* kvpart  = (float*)(ws + 192 * MB);        // 32 MB
    char*  sm      = ws + 264 * MB;
    u16*   wkv_b   = (u16*)sm;                       // 256KB
    float* bkv_re  = (float*)(sm + 256 * 1024);      // 2KB
    u16*   w_o1_b  = (u16*)(sm + 260 * 1024);        // 128KB
    u16*   w_o2_b  = (u16*)(sm + 392 * 1024);        // 128KB
    u16*   wq_effb = (u16*)(sm + 524 * 1024);        // 1MB
    float* beff    = (float*)(sm + 1572 * 1024);     // 8KB

    // K0a: transpose+cast x -> xb
    k_transpose_cast<<<dim3(HW_N / 64, CCH / 64, BATCH), 256, 0, stream>>>(x, xb);
    // K0b: weight prep
    k_weight_prep<<<dim3(1024), 256, 0, stream>>>(w_qkv, b_qkv, w_o1, w_o2,
                                                  wkv_b, bkv_re, w_o1_b, w_o2_b);
    // K1: k/v projection + LN + kv partial sums (round-8 version)
    k_gemm_kv<<<dim3(4, 128, BATCH), 256, 0, stream>>>(
        xb, wkv_b, bkv_re, kln_w, kln_b, vln_w, vln_b, kvpart);
    // K2: reduce partials, build per-batch effective q-weights
    k_wqeff<<<dim3(NHEAD, BATCH), 256, 0, stream>>>(kvpart, w_qkv, b_qkv, wq_effb, beff);
    // K3 fused v11: tri-buffer + bf16 residual from L1-hot xb panel
    k_fused3<<<dim3(2048), 512, 0, stream>>>(
        xb, wq_effb, beff, w_o1_b, b_o1, w_o2_b, b_o2, x, out);
}

// Round 17
// 239.702 us; speedup vs baseline: 1.0668x; 1.0668x over previous
//
#include <hip/hip_runtime.h>
#include <hip/hip_bf16.h>
#include <cstdint>

typedef unsigned short u16;
typedef __attribute__((ext_vector_type(8))) short short8;
typedef __attribute__((ext_vector_type(4))) short short4v;
typedef __attribute__((ext_vector_type(4))) float f32x4;

#define HW_N 16384   // H*W
#define CCH  256     // C
#define BATCH 8
#define NHEAD 8
#define HEADC 32

static __device__ __forceinline__ float bf2f(u16 u){
    union { float f; uint32_t i; } x; x.i = ((uint32_t)u) << 16; return x.f;
}
static __device__ __forceinline__ u16 f2bf(float f){
    union { float f; uint32_t i; } x; x.f = f;
    uint32_t r = x.i + 0x7fffu + ((x.i >> 16) & 1u);   // round-to-nearest-even
    return (u16)(r >> 16);
}

#define GLD16(gp, lp) __builtin_amdgcn_global_load_lds( \
    (const __attribute__((address_space(1))) uint32_t*)(gp), \
    (__attribute__((address_space(3))) uint32_t*)(lp), 16, 0, 0)

// ---------------------------------------------------------------------------
// K0a: x [B,C,N] fp32 -> xb [B*N, C] bf16  (transpose + cast, LDS-tiled)
// ---------------------------------------------------------------------------
__global__ __launch_bounds__(256) void k_transpose_cast(const float* __restrict__ x,
                                                        u16* __restrict__ xb){
    __shared__ float tile[64][65];
    int b = blockIdx.z, ct = blockIdx.y, nt = blockIdx.x;
    int t = threadIdx.x;
    const float* src = x + ((size_t)b * CCH + ct * 64) * HW_N + nt * 64;
    #pragma unroll
    for (int it = 0; it < 16; ++it){
        int f = it * 256 + t;
        int i = f >> 6, j = f & 63;              // i = c-local, j = n-local
        tile[i][j] = src[(size_t)i * HW_N + j];  // coalesced (j fastest)
    }
    __syncthreads();
    u16* dst = xb + ((size_t)b * HW_N + nt * 64) * CCH + ct * 64;
    #pragma unroll
    for (int it = 0; it < 16; ++it){
        int f = it * 256 + t;
        int jj = f >> 6, ii = f & 63;            // jj = n-local, ii = c-local
        dst[(size_t)jj * CCH + ii] = f2bf(tile[ii][jj]);  // coalesced writes
    }
}

// ---------------------------------------------------------------------------
// K0b: weight prep. wkv_b[h*64 + s*32 + d] <- w_qkv row (h*96 + 32 + s*32 + d)
// ---------------------------------------------------------------------------
__global__ __launch_bounds__(256) void k_weight_prep(const float* __restrict__ w_qkv,
                                                     const float* __restrict__ b_qkv,
                                                     const float* __restrict__ w_o1,
                                                     const float* __restrict__ w_o2,
                                                     u16* __restrict__ wkv_b,
                                                     float* __restrict__ bkv_re,
                                                     u16* __restrict__ w_o1_b,
                                                     u16* __restrict__ w_o2_b){
    int id = blockIdx.x * 256 + threadIdx.x;
    if (id < 512 * 256){
        int r = id >> 8, c = id & 255;
        int h = r >> 6, s = (r >> 5) & 1, d = r & 31;
        int srow = h * 96 + 32 + s * 32 + d;
        wkv_b[id] = f2bf(w_qkv[(size_t)srow * 256 + c]);
        if (c == 0) bkv_re[r] = b_qkv[srow];
    } else {
        int id2 = id - 512 * 256;
        if (id2 < 65536)       w_o1_b[id2]         = f2bf(w_o1[id2]);
        else if (id2 < 131072) w_o2_b[id2 - 65536] = f2bf(w_o2[id2 - 65536]);
    }
}

// ---------------------------------------------------------------------------
// K1 fused (round-8 version): kv-projection GEMM + per-head LN + kv partial
// reduce. Single-buffer 32KB staging, __syncthreads schedule.
// ---------------------------------------------------------------------------
__global__ __launch_bounds__(256, 2) void k_gemm_kv(const u16* __restrict__ A,
                                                    const u16* __restrict__ Bt,
                                                    const float* __restrict__ bkv,
                                                    const float* __restrict__ kln_w,
                                                    const float* __restrict__ kln_b,
                                                    const float* __restrict__ vln_w,
                                                    const float* __restrict__ vln_b,
                                                    float* __restrict__ kvpart){
    __shared__ __align__(16) u16 sh[16384];     // staging, then LN'd k/v tiles
    u16* lsA = sh;
    u16* lsB = sh + 8192;

    int lin = blockIdx.x + 4 * (blockIdx.y + 128 * blockIdx.z);
    int bx = (lin >> 3) & 3;
    int rest = (lin & 7) | ((lin >> 5) << 3);
    int by = rest & 127;
    int bz = rest >> 7;

    int row0 = bz * HW_N + by * 128;
    int col0 = bx * 128;

    int t = threadIdx.x;
    int wid = t >> 6, lane = t & 63;
    int wr = wid >> 1, wc = wid & 1;
    int q = lane >> 4, q4 = q * 4, lrow = lane & 15;

    f32x4 acc[4][4];
    #pragma unroll
    for (int i = 0; i < 4; ++i)
        #pragma unroll
        for (int j = 0; j < 4; ++j) acc[i][j] = (f32x4)0.0f;

    for (int kt = 0; kt < 4; ++kt){
        int c0 = kt * 64;
        #pragma unroll
        for (int it = 0; it < 4; ++it){
            int f  = it * 256 + t;
            int fs = f ^ ((f >> 3) & 7);
            int r  = f >> 3, c8 = (fs & 7) * 8;
            GLD16(&A [((size_t)(row0 + r)) * 256 + c0 + c8], &lsA[f * 8]);
            GLD16(&Bt[((size_t)(col0 + r)) * 256 + c0 + c8], &lsB[f * 8]);
        }
        __syncthreads();
        #pragma unroll
        for (int ks = 0; ks < 2; ++ks){
            int lk = q * 8 + ks * 32;
            short8 af[4], bfr[4];
            #pragma unroll
            for (int mi = 0; mi < 4; ++mi){
                int row = wr * 64 + mi * 16 + lrow;
                int e = (row * 64 + lk) ^ ((row & 7) << 3);
                af[mi] = *(const short8*)&lsA[e];
            }
            #pragma unroll
            for (int ni = 0; ni < 4; ++ni){
                int row = wc * 64 + ni * 16 + lrow;
                int e = (row * 64 + lk) ^ ((row & 7) << 3);
                bfr[ni] = *(const short8*)&lsB[e];
            }
            #pragma unroll
            for (int mi = 0; mi < 4; ++mi)
                #pragma unroll
                for (int ni = 0; ni < 4; ++ni)
                    acc[mi][ni] = __builtin_amdgcn_mfma_f32_16x16x32_bf16(
                        bfr[ni], af[mi], acc[mi][ni], 0, 0, 0);   // swapped
        }
        __syncthreads();
    }

    int h = 2 * bx + wc;
    float bv[4][4], lwv[4][4], lbv[4][4];
    #pragma unroll
    for (int ni = 0; ni < 4; ++ni){
        const float* w  = (ni < 2) ? kln_w : vln_w;
        const float* bb = (ni < 2) ? kln_b : vln_b;
        #pragma unroll
        for (int r = 0; r < 4; ++r){
            int de = (ni & 1) * 16 + q4 + r;
            bv[ni][r]  = bkv[col0 + wc * 64 + ni * 16 + q4 + r];
            lwv[ni][r] = w[h * 32 + de];
            lbv[ni][r] = bb[h * 32 + de];
        }
    }

    #pragma unroll
    for (int mi = 0; mi < 4; ++mi){
        float ks = 0.f, ksq = 0.f, vs = 0.f, vsq = 0.f;
        #pragma unroll
        for (int ni = 0; ni < 4; ++ni)
            #pragma unroll
            for (int r = 0; r < 4; ++r){
                float t2 = acc[mi][ni][r] + bv[ni][r];
                acc[mi][ni][r] = t2;
                if (ni < 2){ ks += t2; ksq += t2 * t2; }
                else       { vs += t2; vsq += t2 * t2; }
            }
        ks  += __shfl_xor(ks, 16);  ks  += __shfl_xor(ks, 32);
        ksq += __shfl_xor(ksq, 16); ksq += __shfl_xor(ksq, 32);
        vs  += __shfl_xor(vs, 16);  vs  += __shfl_xor(vs, 32);
        vsq += __shfl_xor(vsq, 16); vsq += __shfl_xor(vsq, 32);
        float muk = ks * 0.03125f, muv = vs * 0.03125f;
        float rsk = rsqrtf(fmaxf(ksq * 0.03125f - muk * muk, 0.f) + 1e-5f);
        float rsv = rsqrtf(fmaxf(vsq * 0.03125f - muv * muv, 0.f) + 1e-5f);
        int n = wr * 64 + mi * 16 + lrow;
        #pragma unroll
        for (int ni = 0; ni < 4; ++ni){
            float mu = (ni < 2) ? muk : muv;
            float rs = (ni < 2) ? rsk : rsv;
            #pragma unroll
            for (int r = 0; r < 4; ++r){
                int d = (ni & 1) * 16 + q4 + r;
                float val = (acc[mi][ni][r] - mu) * rs * lwv[ni][r] + lbv[ni][r];
                int byteoff = ((wc * 2 + (ni >> 1)) << 13) + (d << 8) + (n << 1);
                byteoff ^= (d & 7) << 4;
                *(u16*)((char*)sh + byteoff) = f2bf(val);
            }
        }
    }
    __syncthreads();

    if (wid < 2){
        f32x4 a2[2][2];
        #pragma unroll
        for (int i = 0; i < 2; ++i)
            #pragma unroll
            for (int j = 0; j < 2; ++j) a2[i][j] = (f32x4)0.0f;
        #pragma unroll
        for (int ks2 = 0; ks2 < 4; ++ks2){
            int n0 = q * 8 + ks2 * 32;
            short8 kf[2], vf[2];
            #pragma unroll
            for (int mi = 0; mi < 2; ++mi){
                int d = mi * 16 + lrow;
                int bko = ((wid * 2 + 0) << 13) + (d << 8) + (n0 << 1);
                int bvo = ((wid * 2 + 1) << 13) + (d << 8) + (n0 << 1);
                bko ^= (d & 7) << 4;
                bvo ^= (d & 7) << 4;
                kf[mi] = *(const short8*)((char*)sh + bko);
                vf[mi] = *(const short8*)((char*)sh + bvo);
            }
            #pragma unroll
            for (int mi = 0; mi < 2; ++mi)
                #pragma unroll
                for (int ni = 0; ni < 2; ++ni)
                    a2[mi][ni] = __builtin_amdgcn_mfma_f32_16x16x32_bf16(
                        kf[mi], vf[ni], a2[mi][ni], 0, 0, 0);
        }
        float* dst = kvpart + (((size_t)(bz * 128 + by)) * 8 + 2 * bx + wid) * 1024;
        #pragma unroll
        for (int mi = 0; mi < 2; ++mi)
            #pragma unroll
            for (int ni = 0; ni < 2; ++ni)
                #pragma unroll
                for (int r = 0; r < 4; ++r)
                    dst[(mi * 16 + q4 + r) * 32 + ni * 16 + lrow] = a2[mi][ni][r];
    }
}

// ---------------------------------------------------------------------------
// K2: reduce kv partials (128 chunks), form wq_eff[b,h,e,c] and beff[b,h,e]
// ---------------------------------------------------------------------------
__global__ __launch_bounds__(256) void k_wqeff(const float* __restrict__ kvpart,
                                               const float* __restrict__ w_qkv,
                                               const float* __restrict__ b_qkv,
                                               u16* __restrict__ wq_eff_b,
                                               float* __restrict__ beff){
    __shared__ float kv[1024];   // [d*32 + e]
    int h = blockIdx.x, b = blockIdx.y;
    int t = threadIdx.x;
    f32x4 s = (f32x4)0.0f;
    for (int p = 0; p < 128; ++p){
        f32x4 v = *(const f32x4*)(kvpart + (((size_t)b * 128 + p) * 8 + h) * 1024 + t * 4);
        s = s + v;
    }
    const float invN = 1.0f / (float)HW_N;
    #pragma unroll
    for (int i = 0; i < 4; ++i) kv[t * 4 + i] = s[i] * invN;
    __syncthreads();

    float wcol[32];
    #pragma unroll
    for (int d = 0; d < 32; ++d)
        wcol[d] = w_qkv[((size_t)(h * 96 + d)) * 256 + t];
    for (int e = 0; e < 32; ++e){
        float s2 = 0.f;
        #pragma unroll
        for (int d = 0; d < 32; ++d) s2 += wcol[d] * kv[d * 32 + e];
        wq_eff_b[(((size_t)b * 256) + h * 32 + e) * 256 + t] = f2bf(s2);
    }
    if (t < 32){
        float s3 = 0.f;
        #pragma unroll
        for (int d = 0; d < 32; ++d) s3 += b_qkv[h * 96 + d] * kv[d * 32 + t];
        beff[b * 256 + h * 32 + t] = s3;
    }
}

// ---------------------------------------------------------------------------
// K3 fused v10 (round-15 champion): triple-buffered B rotation -> one
// s_barrier per phase; depth-2 counted prefetch (vmcnt(2) invariant).
// LDS = 32 (I) + 48 (Bs) = 80 KB.
//   stage1: ret = I@wqeff^T + beff + I(resid)       -> I in place
//   stage2: y1  = gelu(I@w_o1^T + b_o1)             -> I in place
//   stage3: out[b,o,n] = I@w_o2^T + b_o2 + x[b,o,n] -> global fp32
// ---------------------------------------------------------------------------
#define STAGE_B(BT, KT, BUF) do {                                             \
    _Pragma("unroll")                                                         \
    for (int it_ = 0; it_ < 2; ++it_){                                        \
        int f_ = it_ * 512 + t;                                               \
        int o_ = f_ >> 2, sl_ = f_ & 3;                                       \
        GLD16(&(BT)[(size_t)o_ * 256 + (KT) * 32 + (sl_ ^ ((o_ >> 1) & 3)) * 8],\
              &(BUF)[f_ * 8]);                                                \
    }                                                                         \
} while(0)

#define ZACC do {                                                             \
    _Pragma("unroll") for (int i_ = 0; i_ < 4; ++i_)                          \
    _Pragma("unroll") for (int j_ = 0; j_ < 2; ++j_)                          \
        acc[i_][j_] = (f32x4)0.0f;                                            \
} while(0)

// Precondition: Bs[0] <- tile0, Bs[1] <- tile1 staged (may be in flight).
// One barrier per phase; stage tile kt+2 into Bs[(kt+2)%3] post-barrier.
#define GEMM_STAGE_TRI(BT, SWAPPED) do {                                      \
    _Pragma("unroll")                                                         \
    for (int kt = 0; kt < 8; ++kt){                                           \
        if (kt < 7) asm volatile("s_waitcnt vmcnt(2)" ::: "memory");          \
        else        asm volatile("s_waitcnt vmcnt(0)" ::: "memory");          \
        __builtin_amdgcn_s_barrier();                                         \
        if (kt < 6) STAGE_B(BT, kt + 2, Bs[(kt + 2) % 3]);                    \
        __builtin_amdgcn_sched_barrier(0);                                    \
        const u16* Bc = Bs[kt % 3];                                           \
        short8 af[4], bf[2];                                                  \
        _Pragma("unroll")                                                     \
        for (int ni = 0; ni < 2; ++ni){                                       \
            int o_ = wid * 32 + ni * 16 + lrow;                               \
            bf[ni] = *(const short8*)((const char*)Bc + o_ * 64               \
                                      + ((q ^ ((o_ >> 1) & 3)) << 4));        \
        }                                                                     \
        _Pragma("unroll")                                                     \
        for (int mi = 0; mi < 4; ++mi){                                       \
            int n_ = mi * 16 + lrow;                                          \
            int sl_ = (kt * 4 + q) ^ (n_ & 7);                                \
            af[mi] = *(const short8*)((const char*)I + n_ * 512 + (sl_ << 4));\
        }                                                                     \
        __builtin_amdgcn_s_setprio(1);                                        \
        _Pragma("unroll")                                                     \
        for (int mi = 0; mi < 4; ++mi)                                        \
            _Pragma("unroll")                                                 \
            for (int ni = 0; ni < 2; ++ni)                                    \
                acc[mi][ni] = (SWAPPED)                                       \
                    ? __builtin_amdgcn_mfma_f32_16x16x32_bf16(                \
                          bf[ni], af[mi], acc[mi][ni], 0, 0, 0)               \
                    : __builtin_amdgcn_mfma_f32_16x16x32_bf16(                \
                          af[mi], bf[ni], acc[mi][ni], 0, 0, 0);              \
        __builtin_amdgcn_s_setprio(0);                                        \
    }                                                                         \
} while(0)

#define LDS_FENCE_BARRIER() do {                                              \
    asm volatile("s_waitcnt lgkmcnt(0)" ::: "memory");                        \
    __builtin_amdgcn_s_barrier();                                             \
    __builtin_amdgcn_sched_barrier(0);                                        \
} while(0)

__global__ __launch_bounds__(512, 4) void k_fused3(const u16* __restrict__ xb,
                                                   const u16* __restrict__ wq_effb,
                                                   const float* __restrict__ beff,
                                                   const u16* __restrict__ w_o1_b,
                                                   const float* __restrict__ b_o1,
                                                   const u16* __restrict__ w_o2_b,
                                                   const float* __restrict__ b_o2,
                                                   const float* __restrict__ x,
                                                   float* __restrict__ out){
    __shared__ __align__(16) u16 I[16384];        // 32 KB persistent panel
    __shared__ __align__(16) u16 Bs[3][8192];     // 3 x 16 KB B rotation

    int d = blockIdx.x;                 // 2048 blocks
    int bz = d & 7, nb = d >> 3;        // batch-per-XCD remap
    size_t row0 = (size_t)bz * HW_N + (size_t)nb * 64;

    int t = threadIdx.x, wid = t >> 6, lane = t & 63;   // wid 0..7
    int lrow = lane & 15, q = lane >> 4, q4 = q * 4;

    const u16* B1 = wq_effb + (size_t)bz * 65536;

    // ---- preload xb panel into I + stage-1 tiles 0,1 (counted wait in loop) ----
    #pragma unroll
    for (int it = 0; it < 4; ++it){
        int f = it * 512 + t;
        int n = f >> 5, slot = f & 31;
        GLD16(&xb[(row0 + n) * 256 + (size_t)((slot ^ (n & 7)) * 8)], &I[f * 8]);
    }
    STAGE_B(B1, 0, Bs[0]);
    STAGE_B(B1, 1, Bs[1]);
    // phase-0 vmcnt(2) waits I-loads + tile0; tile1 stays in flight.

    f32x4 acc[4][2];

    // ================= stage 1: ret = I @ wqeff^T + beff + I ================
    ZACC;
    GEMM_STAGE_TRI(B1, true);
    __syncthreads();                    // all waves done READING I
    #pragma unroll
    for (int ni = 0; ni < 2; ++ni){
        int o0 = wid * 32 + ni * 16 + q4;
        f32x4 be = *(const f32x4*)&beff[bz * 256 + o0];
        #pragma unroll
        for (int mi = 0; mi < 4; ++mi){
            int n = mi * 16 + lrow;
            int byte = (n * 512 + o0 * 2) ^ ((n & 7) << 4);
            short4v rv = *(const short4v*)((const char*)I + byte);
            short4v pk;
            #pragma unroll
            for (int r = 0; r < 4; ++r)
                pk[r] = (short)f2bf(acc[mi][ni][r] + be[r] + bf2f((u16)rv[r]));
            *(short4v*)((char*)I + byte) = pk;
        }
    }
    LDS_FENCE_BARRIER();                // I rewrite visible; Bs reads all past
    STAGE_B(w_o1_b, 0, Bs[0]);          // stage-2 tiles 0,1
    STAGE_B(w_o1_b, 1, Bs[1]);

    // ================= stage 2: y1 = gelu(I @ w_o1^T + b_o1) ================
    ZACC;
    GEMM_STAGE_TRI(w_o1_b, true);
    __syncthreads();
    #pragma unroll
    for (int ni = 0; ni < 2; ++ni){
        int o0 = wid * 32 + ni * 16 + q4;
        f32x4 bo = *(const f32x4*)&b_o1[o0];
        #pragma unroll
        for (int mi = 0; mi < 4; ++mi){
            int n = mi * 16 + lrow;
            int byte = (n * 512 + o0 * 2) ^ ((n & 7) << 4);
            short4v pk;
            #pragma unroll
            for (int r = 0; r < 4; ++r){
                float v = acc[mi][ni][r] + bo[r];
                v = 0.5f * v * (1.0f + erff(v * 0.70710678118654752f));
                pk[r] = (short)f2bf(v);
            }
            *(short4v*)((char*)I + byte) = pk;
        }
    }
    LDS_FENCE_BARRIER();
    STAGE_B(w_o2_b, 0, Bs[0]);          // stage-3 tiles 0,1
    STAGE_B(w_o2_b, 1, Bs[1]);

    // ================= stage 3: out = I @ w_o2^T + b_o2 + x =================
    ZACC;
    GEMM_STAGE_TRI(w_o2_b, false);
    #pragma unroll
    for (int ni = 0; ni < 2; ++ni){
        int o = wid * 32 + ni * 16 + lrow;
        float bo = b_o2[o];
        size_t base = ((size_t)bz * 256 + o) * HW_N + (size_t)nb * 64;
        #pragma unroll
        for (int mi = 0; mi < 4; ++mi){
            int n0 = mi * 16 + q4;
            f32x4 xv = *(const f32x4*)&x[base + n0];
            f32x4 ov;
            #pragma unroll
            for (int r = 0; r < 4; ++r) ov[r] = acc[mi][ni][r] + bo + xv[r];
            *(f32x4*)&out[base + n0] = ov;
        }
    }
}

// ---------------------------------------------------------------------------
extern "C" void kernel_launch(void* const* d_in, const int* in_sizes, int n_in,
                              void* d_out, int out_size, void* d_ws, size_t ws_size,
                              hipStream_t stream){
    const float* x     = (const float*)d_in[0];
    const float* w_qkv = (const float*)d_in[1];
    const float* b_qkv = (const float*)d_in[2];
    const float* kln_w = (const float*)d_in[3];
    const float* kln_b = (const float*)d_in[4];
    const float* vln_w = (const float*)d_in[5];
    const float* vln_b = (const float*)d_in[6];
    const float* w_o1  = (const float*)d_in[7];
    const float* b_o1  = (const float*)d_in[8];
    const float* w_o2  = (const float*)d_in[9];
    const float* b_o2  = (const float*)d_in[10];
    float* out = (float*)d_out;

    const size_t MB = 1u << 20;
    if (ws_size < 266 * MB) return;

    char* ws = (char*)d_ws;
    u16*   xb      = (u16*)(ws);                     // 64 MB
    float* kvpart  = (float*)(ws + 192 * MB);        // 32 MB
    char*  sm      = ws + 264 * MB;
    u16*   wkv_b   = (u16*)sm;                       // 256KB
    float* bkv_re  = (float*)(sm + 256 * 1024);      // 2KB
    u16*   w_o1_b  = (u16*)(sm + 260 * 1024);        // 128KB
    u16*   w_o2_b  = (u16*)(sm + 392 * 1024);        // 128KB
    u16*   wq_effb = (u16*)(sm + 524 * 1024);        // 1MB
    float* beff    = (float*)(sm + 1572 * 1024);     // 8KB

    // K0a: transpose+cast x -> xb
    k_transpose_cast<<<dim3(HW_N / 64, CCH / 64, BATCH), 256, 0, stream>>>(x, xb);
    // K0b: weight prep
    k_weight_prep<<<dim3(1024), 256, 0, stream>>>(w_qkv, b_qkv, w_o1, w_o2,
                                                  wkv_b, bkv_re, w_o1_b, w_o2_b);
    // K1: k/v projection + LN + kv partial sums (round-8 version)
    k_gemm_kv<<<dim3(4, 128, BATCH), 256, 0, stream>>>(
        xb, wkv_b, bkv_re, kln_w, kln_b, vln_w, vln_b, kvpart);
    // K2: reduce partials, build per-batch effective q-weights
    k_wqeff<<<dim3(NHEAD, BATCH), 256, 0, stream>>>(kvpart, w_qkv, b_qkv, wq_effb, beff);
    // K3 fused v10: triple-buffer rotation, one barrier per phase
    k_fused3<<<dim3(2048), 512, 0, stream>>>(
        xb, wq_effb, beff, w_o1_b, b_o1, w_o2_b, b_o2, x, out);
}

// Round 18
// 238.456 us; speedup vs baseline: 1.0723x; 1.0052x over previous
//
#include <hip/hip_runtime.h>
#include <hip/hip_bf16.h>
#include <cstdint>

typedef unsigned short u16;
typedef __attribute__((ext_vector_type(8))) short short8;
typedef __attribute__((ext_vector_type(4))) short short4v;
typedef __attribute__((ext_vector_type(4))) float f32x4;

#define HW_N 16384   // H*W
#define CCH  256     // C
#define BATCH 8
#define NHEAD 8
#define HEADC 32

static __device__ __forceinline__ float bf2f(u16 u){
    union { float f; uint32_t i; } x; x.i = ((uint32_t)u) << 16; return x.f;
}
static __device__ __forceinline__ u16 f2bf(float f){
    union { float f; uint32_t i; } x; x.f = f;
    uint32_t r = x.i + 0x7fffu + ((x.i >> 16) & 1u);   // round-to-nearest-even
    return (u16)(r >> 16);
}

#define GLD16(gp, lp) __builtin_amdgcn_global_load_lds( \
    (const __attribute__((address_space(1))) uint32_t*)(gp), \
    (__attribute__((address_space(3))) uint32_t*)(lp), 16, 0, 0)

// ---------------------------------------------------------------------------
// K0a: x [B,C,N] fp32 -> xb [B*N, C] bf16  (transpose + cast, LDS-tiled)
// ---------------------------------------------------------------------------
__global__ __launch_bounds__(256) void k_transpose_cast(const float* __restrict__ x,
                                                        u16* __restrict__ xb){
    __shared__ float tile[64][65];
    int b = blockIdx.z, ct = blockIdx.y, nt = blockIdx.x;
    int t = threadIdx.x;
    const float* src = x + ((size_t)b * CCH + ct * 64) * HW_N + nt * 64;
    #pragma unroll
    for (int it = 0; it < 16; ++it){
        int f = it * 256 + t;
        int i = f >> 6, j = f & 63;              // i = c-local, j = n-local
        tile[i][j] = src[(size_t)i * HW_N + j];  // coalesced (j fastest)
    }
    __syncthreads();
    u16* dst = xb + ((size_t)b * HW_N + nt * 64) * CCH + ct * 64;
    #pragma unroll
    for (int it = 0; it < 16; ++it){
        int f = it * 256 + t;
        int jj = f >> 6, ii = f & 63;            // jj = n-local, ii = c-local
        dst[(size_t)jj * CCH + ii] = f2bf(tile[ii][jj]);  // coalesced writes
    }
}

// ---------------------------------------------------------------------------
// K0b: weight prep. wkv_b[h*64 + s*32 + d] <- w_qkv row (h*96 + 32 + s*32 + d)
// ---------------------------------------------------------------------------
__global__ __launch_bounds__(256) void k_weight_prep(const float* __restrict__ w_qkv,
                                                     const float* __restrict__ b_qkv,
                                                     const float* __restrict__ w_o1,
                                                     const float* __restrict__ w_o2,
                                                     u16* __restrict__ wkv_b,
                                                     float* __restrict__ bkv_re,
                                                     u16* __restrict__ w_o1_b,
                                                     u16* __restrict__ w_o2_b){
    int id = blockIdx.x * 256 + threadIdx.x;
    if (id < 512 * 256){
        int r = id >> 8, c = id & 255;
        int h = r >> 6, s = (r >> 5) & 1, d = r & 31;
        int srow = h * 96 + 32 + s * 32 + d;
        wkv_b[id] = f2bf(w_qkv[(size_t)srow * 256 + c]);
        if (c == 0) bkv_re[r] = b_qkv[srow];
    } else {
        int id2 = id - 512 * 256;
        if (id2 < 65536)       w_o1_b[id2]         = f2bf(w_o1[id2]);
        else if (id2 < 131072) w_o2_b[id2 - 65536] = f2bf(w_o2[id2 - 65536]);
    }
}

// ---------------------------------------------------------------------------
// K1 fused v3: kv-projection GEMM + per-head LN + kv partial reduce.
// 512 threads / 8 waves (wave grid 4 row-groups x 2 head-cols) -> 16 waves/CU
// at the same 32 KB LDS (was 256 thr = 8 waves/CU, TLP-starved per round-4
// counters: MfmaUtil 8.4%, Occ 33%). Per-thread work halves; LN and the
// kv-partial reduce logic unchanged.
// ---------------------------------------------------------------------------
__global__ __launch_bounds__(512, 4) void k_gemm_kv(const u16* __restrict__ A,
                                                    const u16* __restrict__ Bt,
                                                    const float* __restrict__ bkv,
                                                    const float* __restrict__ kln_w,
                                                    const float* __restrict__ kln_b,
                                                    const float* __restrict__ vln_w,
                                                    const float* __restrict__ vln_b,
                                                    float* __restrict__ kvpart){
    __shared__ __align__(16) u16 sh[16384];     // staging, then LN'd k/v tiles
    u16* lsA = sh;
    u16* lsB = sh + 8192;

    int lin = blockIdx.x + 4 * (blockIdx.y + 128 * blockIdx.z);
    int bx = (lin >> 3) & 3;
    int rest = (lin & 7) | ((lin >> 5) << 3);
    int by = rest & 127;
    int bz = rest >> 7;

    int row0 = bz * HW_N + by * 128;
    int col0 = bx * 128;

    int t = threadIdx.x;
    int wid = t >> 6, lane = t & 63;            // wid 0..7
    int wr = wid >> 1, wc = wid & 1;            // wr 0..3 (32 rows), wc 0..1 (head)
    int q = lane >> 4, q4 = q * 4, lrow = lane & 15;

    f32x4 acc[2][4];
    #pragma unroll
    for (int i = 0; i < 2; ++i)
        #pragma unroll
        for (int j = 0; j < 4; ++j) acc[i][j] = (f32x4)0.0f;

    for (int kt = 0; kt < 4; ++kt){
        int c0 = kt * 64;
        #pragma unroll
        for (int it = 0; it < 2; ++it){
            int f  = it * 512 + t;
            int fs = f ^ ((f >> 3) & 7);
            int r  = f >> 3, c8 = (fs & 7) * 8;
            GLD16(&A [((size_t)(row0 + r)) * 256 + c0 + c8], &lsA[f * 8]);
            GLD16(&Bt[((size_t)(col0 + r)) * 256 + c0 + c8], &lsB[f * 8]);
        }
        __syncthreads();
        #pragma unroll
        for (int ks = 0; ks < 2; ++ks){
            int lk = q * 8 + ks * 32;
            short8 af[2], bfr[4];
            #pragma unroll
            for (int mi = 0; mi < 2; ++mi){
                int row = wr * 32 + mi * 16 + lrow;
                int e = (row * 64 + lk) ^ ((row & 7) << 3);
                af[mi] = *(const short8*)&lsA[e];
            }
            #pragma unroll
            for (int ni = 0; ni < 4; ++ni){
                int row = wc * 64 + ni * 16 + lrow;
                int e = (row * 64 + lk) ^ ((row & 7) << 3);
                bfr[ni] = *(const short8*)&lsB[e];
            }
            #pragma unroll
            for (int mi = 0; mi < 2; ++mi)
                #pragma unroll
                for (int ni = 0; ni < 4; ++ni)
                    acc[mi][ni] = __builtin_amdgcn_mfma_f32_16x16x32_bf16(
                        bfr[ni], af[mi], acc[mi][ni], 0, 0, 0);   // swapped
        }
        __syncthreads();
    }

    int h = 2 * bx + wc;
    float bv[4][4], lwv[4][4], lbv[4][4];
    #pragma unroll
    for (int ni = 0; ni < 4; ++ni){
        const float* w  = (ni < 2) ? kln_w : vln_w;
        const float* bb = (ni < 2) ? kln_b : vln_b;
        #pragma unroll
        for (int r = 0; r < 4; ++r){
            int de = (ni & 1) * 16 + q4 + r;
            bv[ni][r]  = bkv[col0 + wc * 64 + ni * 16 + q4 + r];
            lwv[ni][r] = w[h * 32 + de];
            lbv[ni][r] = bb[h * 32 + de];
        }
    }

    #pragma unroll
    for (int mi = 0; mi < 2; ++mi){
        float ks = 0.f, ksq = 0.f, vs = 0.f, vsq = 0.f;
        #pragma unroll
        for (int ni = 0; ni < 4; ++ni)
            #pragma unroll
            for (int r = 0; r < 4; ++r){
                float t2 = acc[mi][ni][r] + bv[ni][r];
                acc[mi][ni][r] = t2;
                if (ni < 2){ ks += t2; ksq += t2 * t2; }
                else       { vs += t2; vsq += t2 * t2; }
            }
        ks  += __shfl_xor(ks, 16);  ks  += __shfl_xor(ks, 32);
        ksq += __shfl_xor(ksq, 16); ksq += __shfl_xor(ksq, 32);
        vs  += __shfl_xor(vs, 16);  vs  += __shfl_xor(vs, 32);
        vsq += __shfl_xor(vsq, 16); vsq += __shfl_xor(vsq, 32);
        float muk = ks * 0.03125f, muv = vs * 0.03125f;
        float rsk = rsqrtf(fmaxf(ksq * 0.03125f - muk * muk, 0.f) + 1e-5f);
        float rsv = rsqrtf(fmaxf(vsq * 0.03125f - muv * muv, 0.f) + 1e-5f);
        int n = wr * 32 + mi * 16 + lrow;
        #pragma unroll
        for (int ni = 0; ni < 4; ++ni){
            float mu = (ni < 2) ? muk : muv;
            float rs = (ni < 2) ? rsk : rsv;
            #pragma unroll
            for (int r = 0; r < 4; ++r){
                int d = (ni & 1) * 16 + q4 + r;
                float val = (acc[mi][ni][r] - mu) * rs * lwv[ni][r] + lbv[ni][r];
                int byteoff = ((wc * 2 + (ni >> 1)) << 13) + (d << 8) + (n << 1);
                byteoff ^= (d & 7) << 4;
                *(u16*)((char*)sh + byteoff) = f2bf(val);
            }
        }
    }
    __syncthreads();

    if (wid < 2){
        f32x4 a2[2][2];
        #pragma unroll
        for (int i = 0; i < 2; ++i)
            #pragma unroll
            for (int j = 0; j < 2; ++j) a2[i][j] = (f32x4)0.0f;
        #pragma unroll
        for (int ks2 = 0; ks2 < 4; ++ks2){
            int n0 = q * 8 + ks2 * 32;
            short8 kf[2], vf[2];
            #pragma unroll
            for (int mi = 0; mi < 2; ++mi){
                int d = mi * 16 + lrow;
                int bko = ((wid * 2 + 0) << 13) + (d << 8) + (n0 << 1);
                int bvo = ((wid * 2 + 1) << 13) + (d << 8) + (n0 << 1);
                bko ^= (d & 7) << 4;
                bvo ^= (d & 7) << 4;
                kf[mi] = *(const short8*)((char*)sh + bko);
                vf[mi] = *(const short8*)((char*)sh + bvo);
            }
            #pragma unroll
            for (int mi = 0; mi < 2; ++mi)
                #pragma unroll
                for (int ni = 0; ni < 2; ++ni)
                    a2[mi][ni] = __builtin_amdgcn_mfma_f32_16x16x32_bf16(
                        kf[mi], vf[ni], a2[mi][ni], 0, 0, 0);
        }
        float* dst = kvpart + (((size_t)(bz * 128 + by)) * 8 + 2 * bx + wid) * 1024;
        #pragma unroll
        for (int mi = 0; mi < 2; ++mi)
            #pragma unroll
            for (int ni = 0; ni < 2; ++ni)
                #pragma unroll
                for (int r = 0; r < 4; ++r)
                    dst[(mi * 16 + q4 + r) * 32 + ni * 16 + lrow] = a2[mi][ni][r];
    }
}

// ---------------------------------------------------------------------------
// K2: reduce kv partials (128 chunks), form wq_eff[b,h,e,c] and beff[b,h,e]
// ---------------------------------------------------------------------------
__global__ __launch_bounds__(256) void k_wqeff(const float* __restrict__ kvpart,
                                               const float* __restrict__ w_qkv,
                                               const float* __restrict__ b_qkv,
                                               u16* __restrict__ wq_eff_b,
                                               float* __restrict__ beff){
    __shared__ float kv[1024];   // [d*32 + e]
    int h = blockIdx.x, b = blockIdx.y;
    int t = threadIdx.x;
    f32x4 s = (f32x4)0.0f;
    for (int p = 0; p < 128; ++p){
        f32x4 v = *(const f32x4*)(kvpart + (((size_t)b * 128 + p) * 8 + h) * 1024 + t * 4);
        s = s + v;
    }
    const float invN = 1.0f / (float)HW_N;
    #pragma unroll
    for (int i = 0; i < 4; ++i) kv[t * 4 + i] = s[i] * invN;
    __syncthreads();

    float wcol[32];
    #pragma unroll
    for (int d = 0; d < 32; ++d)
        wcol[d] = w_qkv[((size_t)(h * 96 + d)) * 256 + t];
    for (int e = 0; e < 32; ++e){
        float s2 = 0.f;
        #pragma unroll
        for (int d = 0; d < 32; ++d) s2 += wcol[d] * kv[d * 32 + e];
        wq_eff_b[(((size_t)b * 256) + h * 32 + e) * 256 + t] = f2bf(s2);
    }
    if (t < 32){
        float s3 = 0.f;
        #pragma unroll
        for (int d = 0; d < 32; ++d) s3 += b_qkv[h * 96 + d] * kv[d * 32 + t];
        beff[b * 256 + h * 32 + t] = s3;
    }
}

// ---------------------------------------------------------------------------
// K3 fused v10 (round-15 champion): triple-buffered B rotation -> one
// s_barrier per phase; depth-2 counted prefetch (vmcnt(2) invariant).
// LDS = 32 (I) + 48 (Bs) = 80 KB.
//   stage1: ret = I@wqeff^T + beff + I(resid)       -> I in place
//   stage2: y1  = gelu(I@w_o1^T + b_o1)             -> I in place
//   stage3: out[b,o,n] = I@w_o2^T + b_o2 + x[b,o,n] -> global fp32
// ---------------------------------------------------------------------------
#define STAGE_B(BT, KT, BUF) do {                                             \
    _Pragma("unroll")                                                         \
    for (int it_ = 0; it_ < 2; ++it_){                                        \
        int f_ = it_ * 512 + t;                                               \
        int o_ = f_ >> 2, sl_ = f_ & 3;                                       \
        GLD16(&(BT)[(size_t)o_ * 256 + (KT) * 32 + (sl_ ^ ((o_ >> 1) & 3)) * 8],\
              &(BUF)[f_ * 8]);                                                \
    }                                                                         \
} while(0)

#define ZACC do {                                                             \
    _Pragma("unroll") for (int i_ = 0; i_ < 4; ++i_)                          \
    _Pragma("unroll") for (int j_ = 0; j_ < 2; ++j_)                          \
        acc[i_][j_] = (f32x4)0.0f;                                            \
} while(0)

// Precondition: Bs[0] <- tile0, Bs[1] <- tile1 staged (may be in flight).
// One barrier per phase; stage tile kt+2 into Bs[(kt+2)%3] post-barrier.
#define GEMM_STAGE_TRI(BT, SWAPPED) do {                                      \
    _Pragma("unroll")                                                         \
    for (int kt = 0; kt < 8; ++kt){                                           \
        if (kt < 7) asm volatile("s_waitcnt vmcnt(2)" ::: "memory");          \
        else        asm volatile("s_waitcnt vmcnt(0)" ::: "memory");          \
        __builtin_amdgcn_s_barrier();                                         \
        if (kt < 6) STAGE_B(BT, kt + 2, Bs[(kt + 2) % 3]);                    \
        __builtin_amdgcn_sched_barrier(0);                                    \
        const u16* Bc = Bs[kt % 3];                                           \
        short8 af[4], bf[2];                                                  \
        _Pragma("unroll")                                                     \
        for (int ni = 0; ni < 2; ++ni){                                       \
            int o_ = wid * 32 + ni * 16 + lrow;                               \
            bf[ni] = *(const short8*)((const char*)Bc + o_ * 64               \
                                      + ((q ^ ((o_ >> 1) & 3)) << 4));        \
        }                                                                     \
        _Pragma("unroll")                                                     \
        for (int mi = 0; mi < 4; ++mi){                                       \
            int n_ = mi * 16 + lrow;                                          \
            int sl_ = (kt * 4 + q) ^ (n_ & 7);                                \
            af[mi] = *(const short8*)((const char*)I + n_ * 512 + (sl_ << 4));\
        }                                                                     \
        __builtin_amdgcn_s_setprio(1);                                        \
        _Pragma("unroll")                                                     \
        for (int mi = 0; mi < 4; ++mi)                                        \
            _Pragma("unroll")                                                 \
            for (int ni = 0; ni < 2; ++ni)                                    \
                acc[mi][ni] = (SWAPPED)                                       \
                    ? __builtin_amdgcn_mfma_f32_16x16x32_bf16(                \
                          bf[ni], af[mi], acc[mi][ni], 0, 0, 0)               \
                    : __builtin_amdgcn_mfma_f32_16x16x32_bf16(                \
                          af[mi], bf[ni], acc[mi][ni], 0, 0, 0);              \
        __builtin_amdgcn_s_setprio(0);                                        \
    }                                                                         \
} while(0)

#define LDS_FENCE_BARRIER() do {                                              \
    asm volatile("s_waitcnt lgkmcnt(0)" ::: "memory");                        \
    __builtin_amdgcn_s_barrier();                                             \
    __builtin_amdgcn_sched_barrier(0);                                        \
} while(0)

__global__ __launch_bounds__(512, 4) void k_fused3(const u16* __restrict__ xb,
                                                   const u16* __restrict__ wq_effb,
                                                   const float* __restrict__ beff,
                                                   const u16* __restrict__ w_o1_b,
                                                   const float* __restrict__ b_o1,
                                                   const u16* __restrict__ w_o2_b,
                                                   const float* __restrict__ b_o2,
                                                   const float* __restrict__ x,
                                                   float* __restrict__ out){
    __shared__ __align__(16) u16 I[16384];        // 32 KB persistent panel
    __shared__ __align__(16) u16 Bs[3][8192];     // 3 x 16 KB B rotation

    int d = blockIdx.x;                 // 2048 blocks
    int bz = d & 7, nb = d >> 3;        // batch-per-XCD remap
    size_t row0 = (size_t)bz * HW_N + (size_t)nb * 64;

    int t = threadIdx.x, wid = t >> 6, lane = t & 63;   // wid 0..7
    int lrow = lane & 15, q = lane >> 4, q4 = q * 4;

    const u16* B1 = wq_effb + (size_t)bz * 65536;

    // ---- preload xb panel into I + stage-1 tiles 0,1 (counted wait in loop) ----
    #pragma unroll
    for (int it = 0; it < 4; ++it){
        int f = it * 512 + t;
        int n = f >> 5, slot = f & 31;
        GLD16(&xb[(row0 + n) * 256 + (size_t)((slot ^ (n & 7)) * 8)], &I[f * 8]);
    }
    STAGE_B(B1, 0, Bs[0]);
    STAGE_B(B1, 1, Bs[1]);
    // phase-0 vmcnt(2) waits I-loads + tile0; tile1 stays in flight.

    f32x4 acc[4][2];

    // ================= stage 1: ret = I @ wqeff^T + beff + I ================
    ZACC;
    GEMM_STAGE_TRI(B1, true);
    __syncthreads();                    // all waves done READING I
    #pragma unroll
    for (int ni = 0; ni < 2; ++ni){
        int o0 = wid * 32 + ni * 16 + q4;
        f32x4 be = *(const f32x4*)&beff[bz * 256 + o0];
        #pragma unroll
        for (int mi = 0; mi < 4; ++mi){
            int n = mi * 16 + lrow;
            int byte = (n * 512 + o0 * 2) ^ ((n & 7) << 4);
            short4v rv = *(const short4v*)((const char*)I + byte);
            short4v pk;
            #pragma unroll
            for (int r = 0; r < 4; ++r)
                pk[r] = (short)f2bf(acc[mi][ni][r] + be[r] + bf2f((u16)rv[r]));
            *(short4v*)((char*)I + byte) = pk;
        }
    }
    LDS_FENCE_BARRIER();                // I rewrite visible; Bs reads all past
    STAGE_B(w_o1_b, 0, Bs[0]);          // stage-2 tiles 0,1
    STAGE_B(w_o1_b, 1, Bs[1]);

    // ================= stage 2: y1 = gelu(I @ w_o1^T + b_o1) ================
    ZACC;
    GEMM_STAGE_TRI(w_o1_b, true);
    __syncthreads();
    #pragma unroll
    for (int ni = 0; ni < 2; ++ni){
        int o0 = wid * 32 + ni * 16 + q4;
        f32x4 bo = *(const f32x4*)&b_o1[o0];
        #pragma unroll
        for (int mi = 0; mi < 4; ++mi){
            int n = mi * 16 + lrow;
            int byte = (n * 512 + o0 * 2) ^ ((n & 7) << 4);
            short4v pk;
            #pragma unroll
            for (int r = 0; r < 4; ++r){
                float v = acc[mi][ni][r] + bo[r];
                v = 0.5f * v * (1.0f + erff(v * 0.70710678118654752f));
                pk[r] = (short)f2bf(v);
            }
            *(short4v*)((char*)I + byte) = pk;
        }
    }
    LDS_FENCE_BARRIER();
    STAGE_B(w_o2_b, 0, Bs[0]);          // stage-3 tiles 0,1
    STAGE_B(w_o2_b, 1, Bs[1]);

    // ================= stage 3: out = I @ w_o2^T + b_o2 + x =================
    ZACC;
    GEMM_STAGE_TRI(w_o2_b, false);
    #pragma unroll
    for (int ni = 0; ni < 2; ++ni){
        int o = wid * 32 + ni * 16 + lrow;
        float bo = b_o2[o];
        size_t base = ((size_t)bz * 256 + o) * HW_N + (size_t)nb * 64;
        #pragma unroll
        for (int mi = 0; mi < 4; ++mi){
            int n0 = mi * 16 + q4;
            f32x4 xv = *(const f32x4*)&x[base + n0];
            f32x4 ov;
            #pragma unroll
            for (int r = 0; r < 4; ++r) ov[r] = acc[mi][ni][r] + bo + xv[r];
            *(f32x4*)&out[base + n0] = ov;
        }
    }
}

// ---------------------------------------------------------------------------
extern "C" void kernel_launch(void* const* d_in, const int* in_sizes, int n_in,
                              void* d_out, int out_size, void* d_ws, size_t ws_size,
                              hipStream_t stream){
    const float* x     = (const float*)d_in[0];
    const float* w_qkv = (const float*)d_in[1];
    const float* b_qkv = (const float*)d_in[2];
    const float* kln_w = (const float*)d_in[3];
    const float* kln_b = (const float*)d_in[4];
    const float* vln_w = (const float*)d_in[5];
    const float* vln_b = (const float*)d_in[6];
    const float* w_o1  = (const float*)d_in[7];
    const float* b_o1  = (const float*)d_in[8];
    const float* w_o2  = (const float*)d_in[9];
    const float* b_o2  = (const float*)d_in[10];
    float* out = (float*)d_out;

    const size_t MB = 1u << 20;
    if (ws_size < 266 * MB) return;

    char* ws = (char*)d_ws;
    u16*   xb      = (u16*)(ws);                     // 64 MB
    float* kvpart  = (float*)(ws + 192 * MB);        // 32 MB
    char*  sm      = ws + 264 * MB;
    u16*   wkv_b   = (u16*)sm;                       // 256KB
    float* bkv_re  = (float*)(sm + 256 * 1024);      // 2KB
    u16*   w_o1_b  = (u16*)(sm + 260 * 1024);        // 128KB
    u16*   w_o2_b  = (u16*)(sm + 392 * 1024);        // 128KB
    u16*   wq_effb = (u16*)(sm + 524 * 1024);        // 1MB
    float* beff    = (float*)(sm + 1572 * 1024);     // 8KB

    // K0a: transpose+cast x -> xb
    k_transpose_cast<<<dim3(HW_N / 64, CCH / 64, BATCH), 256, 0, stream>>>(x, xb);
    // K0b: weight prep
    k_weight_prep<<<dim3(1024), 256, 0, stream>>>(w_qkv, b_qkv, w_o1, w_o2,
                                                  wkv_b, bkv_re, w_o1_b, w_o2_b);
    // K1: k/v projection + LN + kv partial sums (512 threads / 8 waves)
    k_gemm_kv<<<dim3(4, 128, BATCH), 512, 0, stream>>>(
        xb, wkv_b, bkv_re, kln_w, kln_b, vln_w, vln_b, kvpart);
    // K2: reduce partials, build per-batch effective q-weights
    k_wqeff<<<dim3(NHEAD, BATCH), 256, 0, stream>>>(kvpart, w_qkv, b_qkv, wq_effb, beff);
    // K3 fused v10: triple-buffer rotation, one barrier per phase
    k_fused3<<<dim3(2048), 512, 0, stream>>>(
        xb, wq_effb, beff, w_o1_b, b_o1, w_o2_b, b_o2, x, out);
}